// Round 10
// baseline (288.990 us; speedup 1.0000x reference)
//
#include <hip/hip_runtime.h>
#include <hip/hip_bf16.h>
#include <math.h>

#define N_TOK 4096
#define D_DIM 512
#define E_NUM 8
#define H_DIM 256

typedef __attribute__((ext_vector_type(8))) short short8v;   // 8 bf16
typedef __attribute__((ext_vector_type(4))) float floatx4;   // MFMA acc

union U4S8 { uint4 u; short8v s; };

__device__ inline floatx4 mfma_bf16(short8v a, short8v b, floatx4 c) {
    return __builtin_amdgcn_mfma_f32_16x16x32_bf16(a, b, c, 0, 0, 0);
}

__device__ inline unsigned short f2bf(float f) {           // RNE fp32->bf16
    union { float f; unsigned u; } v; v.f = f;
    unsigned r = v.u + 0x7FFFu + ((v.u >> 16) & 1u);
    return (unsigned short)(r >> 16);
}
__device__ inline unsigned pack2(float a, float b) {
    return (unsigned)f2bf(a) | ((unsigned)f2bf(b) << 16);
}
__device__ inline void calc_offs(const int* __restrict__ counts, int* offs) {
    int a = 0;
    #pragma unroll
    for (int e = 0; e < E_NUM; e++) { offs[e] = a; a += counts[e]; }
    offs[E_NUM] = a;
}

// ---------------------------------------------------------------------------
__global__ void init_kernel(int* counts, int* nextp) {
    int t = threadIdx.x;
    if (t < 16) { counts[t] = 0; nextp[t] = 0; }
}

// ---------------------------------------------------------------------------
// router v2 (unchanged): wave per 4 tokens, R in regs, exact fp32 top-2
// ---------------------------------------------------------------------------
__global__ __launch_bounds__(256)
void router_kernel(const float* __restrict__ x, const float* __restrict__ router,
                   int* __restrict__ topk_idx, float* __restrict__ topk_sc,
                   int* __restrict__ counts) {
    __shared__ int csh[E_NUM];
    int t = threadIdx.x;
    if (t < E_NUM) csh[t] = 0;
    __syncthreads();

    int wave = t >> 6, lane = t & 63;
    float R[8][8];
    #pragma unroll
    for (int q = 0; q < 8; q++) {
        #pragma unroll
        for (int h = 0; h < 2; h++) {
            float4 v = *reinterpret_cast<const float4*>(
                router + (size_t)(lane * 8 + q) * E_NUM + h * 4);
            R[q][h * 4 + 0] = v.x; R[q][h * 4 + 1] = v.y;
            R[q][h * 4 + 2] = v.z; R[q][h * 4 + 3] = v.w;
        }
    }
    int cnt[E_NUM];
    #pragma unroll
    for (int e = 0; e < E_NUM; e++) cnt[e] = 0;

    #pragma unroll
    for (int it = 0; it < 4; it++) {
        int n = (blockIdx.x * 4 + wave) * 4 + it;
        const float* xr = x + (size_t)n * D_DIM + lane * 8;
        float4 xa = *reinterpret_cast<const float4*>(xr);
        float4 xb = *reinterpret_cast<const float4*>(xr + 4);
        float xs[8] = {xa.x, xa.y, xa.z, xa.w, xb.x, xb.y, xb.z, xb.w};

        float acc[E_NUM];
        #pragma unroll
        for (int e = 0; e < E_NUM; e++) acc[e] = 0.f;
        #pragma unroll
        for (int q = 0; q < 8; q++)
            #pragma unroll
            for (int e = 0; e < E_NUM; e++)
                acc[e] = fmaf(xs[q], R[q][e], acc[e]);
        #pragma unroll
        for (int s = 1; s < 64; s <<= 1) {
            #pragma unroll
            for (int e = 0; e < E_NUM; e++)
                acc[e] += __shfl_xor(acc[e], s);
        }
        float mx = acc[0];
        #pragma unroll
        for (int e = 1; e < E_NUM; e++) mx = fmaxf(mx, acc[e]);
        float p[E_NUM], s = 0.f;
        #pragma unroll
        for (int e = 0; e < E_NUM; e++) { p[e] = expf(acc[e] - mx); s += p[e]; }
        float inv = 1.f / s;

        int i0 = 0; float p0 = p[0];
        #pragma unroll
        for (int e = 1; e < E_NUM; e++)
            if (p[e] > p0) { p0 = p[e]; i0 = e; }
        int i1 = -1; float p1 = -1.f;
        #pragma unroll
        for (int e = 0; e < E_NUM; e++)
            if (e != i0 && p[e] > p1) { p1 = p[e]; i1 = e; }

        if (lane == 0) {
            topk_idx[n * 2 + 0] = i0;
            topk_idx[n * 2 + 1] = i1;
            topk_sc[n * 2 + 0]  = p0 * inv;
            topk_sc[n * 2 + 1]  = p1 * inv;
            #pragma unroll
            for (int e = 0; e < E_NUM; e++)
                cnt[e] += (i0 == e) + (i1 == e);
        }
    }
    if (lane == 0) {
        #pragma unroll
        for (int e = 0; e < E_NUM; e++)
            if (cnt[e]) atomicAdd(&csh[e], cnt[e]);
    }
    __syncthreads();
    if (t < E_NUM && csh[t]) atomicAdd(&counts[t], csh[t]);
}

// ---------------------------------------------------------------------------
// place (unchanged)
// ---------------------------------------------------------------------------
__global__ __launch_bounds__(256)
void place_kernel(const int* __restrict__ topk_idx, const float* __restrict__ topk_sc,
                  const int* __restrict__ counts, int* __restrict__ nextp,
                  int* __restrict__ list_tok, float* __restrict__ list_sc) {
    int offs[E_NUM + 1];
    calc_offs(counts, offs);
    int n = blockIdx.x * 256 + threadIdx.x;
    int lane = threadIdx.x & 63;
    for (int k = 0; k < 2; k++) {
        int e = topk_idx[n * 2 + k];
        float sc = topk_sc[n * 2 + k];
        #pragma unroll
        for (int ee = 0; ee < E_NUM; ee++) {
            unsigned long long m = __ballot(e == ee);
            if (m == 0ull) continue;
            int leader = __ffsll((long long)m) - 1;
            int base = 0;
            if (lane == leader) base = atomicAdd(&nextp[ee], (int)__popcll(m));
            base = __shfl(base, leader);
            if (e == ee) {
                int pos = base + (int)__popcll(m & ((1ull << lane) - 1ull));
                int slot = offs[ee] + pos;
                list_tok[slot] = n;
                list_sc[slot]  = sc;
            }
        }
    }
}

// ---------------------------------------------------------------------------
// prep_frag (unchanged): repack weights into MFMA-native fragment streams.
// ---------------------------------------------------------------------------
__global__ __launch_bounds__(256)
void prep_frag(const float* __restrict__ Wg, const float* __restrict__ Wu,
               const float* __restrict__ shg, const float* __restrict__ shu,
               const float* __restrict__ Wd, const float* __restrict__ shd,
               unsigned short* __restrict__ WguF, unsigned short* __restrict__ WdF) {
    int wid = threadIdx.x >> 6, lane = threadIdx.x & 63;
    int job = blockIdx.x * 4 + wid;
    int kg = lane >> 4, ln = lane & 15;
    if (job < 288) {                                   // gate/up family
        int e = job >> 5, r = job & 31, gu = r >> 4, nt = r & 15;
        const float* S = (e < E_NUM) ? ((gu ? Wu : Wg) + (size_t)e * 131072)
                                     : (gu ? shu : shg);
        unsigned short* D = WguF + ((size_t)((e * 2 + gu) * 16 + nt) * 16) * 512 + lane * 8;
        for (int ks = 0; ks < 16; ks++) {
            float v[8];
            #pragma unroll
            for (int j = 0; j < 8; j++)
                v[j] = S[(size_t)(ks * 32 + kg * 8 + j) * H_DIM + nt * 16 + ln];
            uint4 o;
            o.x = pack2(v[0], v[1]); o.y = pack2(v[2], v[3]);
            o.z = pack2(v[4], v[5]); o.w = pack2(v[6], v[7]);
            *reinterpret_cast<uint4*>(D + ks * 512) = o;
        }
    } else if (job < 576) {                            // down family
        int j2 = job - 288;
        int e = j2 >> 5, nt = j2 & 31;
        const float* S = (e < E_NUM) ? (Wd + (size_t)e * 131072) : shd;
        unsigned short* D = WdF + ((size_t)(e * 32 + nt) * 8) * 512 + lane * 8;
        for (int ks = 0; ks < 8; ks++) {
            float v[8];
            #pragma unroll
            for (int j = 0; j < 8; j++)
                v[j] = S[(size_t)(ks * 32 + kg * 8 + j) * D_DIM + nt * 16 + ln];
            uint4 o;
            o.x = pack2(v[0], v[1]); o.y = pack2(v[2], v[3]);
            o.z = pack2(v[4], v[5]); o.w = pack2(v[6], v[7]);
            *reinterpret_cast<uint4*>(D + ks * 512) = o;
        }
    }
}

// ---------------------------------------------------------------------------
// gemm1 v4: barrier-free, LDS-free, rt=4 -> wave = 64 rows x 64 cols.
// Per kstep: 16 loads feed 32 MFMAs (4x arithmetic intensity vs v3).
// grid (16, 4, 9): stile64 = bx*4+wid, nt0 = by*4, z = expert (8=shared).
// ---------------------------------------------------------------------------
__global__ __launch_bounds__(256, 1)
void gemm1_kernel(const float* __restrict__ x, const unsigned short* __restrict__ WguF,
                  const int* __restrict__ counts, const int* __restrict__ list_tok,
                  const float* __restrict__ list_sc,
                  unsigned short* __restrict__ H1s, unsigned short* __restrict__ H1r) {
    int ez = blockIdx.z;
    int offs[E_NUM + 1];
    calc_offs(counts, offs);
    int beg = 0, M;
    if (ez == E_NUM) { M = N_TOK; }
    else { beg = offs[ez]; M = counts[ez]; }
    int wid = threadIdx.x >> 6, lane = threadIdx.x & 63;
    int stile = blockIdx.x * 4 + wid;              // 64-row tile id
    if (stile * 64 >= M) return;
    int nt0 = blockIdx.y * 4;
    int kg = lane >> 4, ln = lane & 15;

    const float* ap[4];
    #pragma unroll
    for (int rt = 0; rt < 4; rt++) {
        int m_lane = stile * 64 + rt * 16 + ln;
        int srow;
        if (ez == E_NUM) srow = m_lane < M ? m_lane : M - 1;
        else srow = list_tok[beg + (m_lane < M ? m_lane : M - 1)];
        ap[rt] = x + (size_t)srow * D_DIM + kg * 8;
    }

    const unsigned short* bgp = WguF + ((size_t)((ez * 2 + 0) * 16 + nt0) * 16) * 512 + lane * 8;
    const unsigned short* bup = WguF + ((size_t)((ez * 2 + 1) * 16 + nt0) * 16) * 512 + lane * 8;

    floatx4 zf = {0.f, 0.f, 0.f, 0.f};
    floatx4 accg[4][4], accu[4][4];
    #pragma unroll
    for (int rt = 0; rt < 4; rt++)
        #pragma unroll
        for (int nf = 0; nf < 4; nf++) { accg[rt][nf] = zf; accu[rt][nf] = zf; }

    float4 aL[2][4], aH[2][4];
    uint4 vg[2][4], vu[2][4];
    #pragma unroll
    for (int rt = 0; rt < 4; rt++) {
        aL[0][rt] = *reinterpret_cast<const float4*>(ap[rt]);
        aH[0][rt] = *reinterpret_cast<const float4*>(ap[rt] + 4);
    }
    #pragma unroll
    for (int nf = 0; nf < 4; nf++) {
        vg[0][nf] = *reinterpret_cast<const uint4*>(bgp + nf * 8192);
        vu[0][nf] = *reinterpret_cast<const uint4*>(bup + nf * 8192);
    }
    #pragma unroll
    for (int ks = 0; ks < 16; ks++) {
        const int cur = ks & 1, nxt = cur ^ 1;
        if (ks < 15) {
            #pragma unroll
            for (int rt = 0; rt < 4; rt++) {
                aL[nxt][rt] = *reinterpret_cast<const float4*>(ap[rt] + (ks + 1) * 32);
                aH[nxt][rt] = *reinterpret_cast<const float4*>(ap[rt] + (ks + 1) * 32 + 4);
            }
            #pragma unroll
            for (int nf = 0; nf < 4; nf++) {
                vg[nxt][nf] = *reinterpret_cast<const uint4*>(bgp + nf * 8192 + (ks + 1) * 512);
                vu[nxt][nf] = *reinterpret_cast<const uint4*>(bup + nf * 8192 + (ks + 1) * 512);
            }
        }
        U4S8 A[4];
        #pragma unroll
        for (int rt = 0; rt < 4; rt++) {
            A[rt].u.x = pack2(aL[cur][rt].x, aL[cur][rt].y);
            A[rt].u.y = pack2(aL[cur][rt].z, aL[cur][rt].w);
            A[rt].u.z = pack2(aH[cur][rt].x, aH[cur][rt].y);
            A[rt].u.w = pack2(aH[cur][rt].z, aH[cur][rt].w);
        }
        #pragma unroll
        for (int nf = 0; nf < 4; nf++) {
            U4S8 g, u; g.u = vg[cur][nf]; u.u = vu[cur][nf];
            #pragma unroll
            for (int rt = 0; rt < 4; rt++) {
                accg[rt][nf] = mfma_bf16(A[rt].s, g.s, accg[rt][nf]);
                accu[rt][nf] = mfma_bf16(A[rt].s, u.s, accu[rt][nf]);
            }
        }
    }

    // epilogue: C/D row=(l>>4)*4+j, col=l&15. silu(g)*u (*score), bf16 store.
    #pragma unroll
    for (int rt = 0; rt < 4; rt++) {
        #pragma unroll
        for (int j = 0; j < 4; j++) {
            int m = stile * 64 + rt * 16 + kg * 4 + j;
            if (m >= M) continue;
            float sc = 1.f;
            unsigned short* drow;
            if (ez == E_NUM) drow = H1s + (size_t)m * H_DIM;
            else { sc = list_sc[beg + m]; drow = H1r + (size_t)(beg + m) * H_DIM; }
            #pragma unroll
            for (int nf = 0; nf < 4; nf++) {
                float g = accg[rt][nf][j];
                float u = accu[rt][nf][j];
                float h = g / (1.f + expf(-g)) * u * sc;
                drow[(nt0 + nf) * 16 + ln] = f2bf(h);
            }
        }
    }
}

// ---------------------------------------------------------------------------
// down v4: barrier-free, LDS-free, rt=4 -> wave = 64 rows x 64 cols, 8 ksteps.
// routed=0: shared expert, plain stores cover all of out (runs first).
// routed=1: per-expert atomicAdd.
// ---------------------------------------------------------------------------
__global__ __launch_bounds__(256, 1)
void down_kernel(const unsigned short* __restrict__ H1s, const unsigned short* __restrict__ H1r,
                 const unsigned short* __restrict__ WdF, const int* __restrict__ counts,
                 const int* __restrict__ list_tok, float* __restrict__ out, int routed) {
    int beg = 0, M, eidx;
    if (routed) {
        int e = blockIdx.z;
        int offs[E_NUM + 1];
        calc_offs(counts, offs);
        beg = offs[e]; M = counts[e]; eidx = e;
    } else { M = N_TOK; eidx = E_NUM; }
    int wid = threadIdx.x >> 6, lane = threadIdx.x & 63;
    int stile = blockIdx.x * 4 + wid;
    if (stile * 64 >= M) return;
    int nt0 = blockIdx.y * 4;
    int kg = lane >> 4, ln = lane & 15;

    const unsigned short* H1 = routed ? H1r : H1s;
    const unsigned short* ap[4];
    #pragma unroll
    for (int rt = 0; rt < 4; rt++) {
        int m_lane = stile * 64 + rt * 16 + ln;
        int idx = m_lane < M ? m_lane : M - 1;
        ap[rt] = H1 + (size_t)(beg + idx) * H_DIM + kg * 8;
    }
    const unsigned short* bp = WdF + ((size_t)(eidx * 32 + nt0) * 8) * 512 + lane * 8;

    floatx4 zf = {0.f, 0.f, 0.f, 0.f};
    floatx4 acc[4][4];
    #pragma unroll
    for (int rt = 0; rt < 4; rt++)
        #pragma unroll
        for (int nf = 0; nf < 4; nf++) acc[rt][nf] = zf;

    uint4 av[2][4], bv[2][4];
    #pragma unroll
    for (int rt = 0; rt < 4; rt++)
        av[0][rt] = *reinterpret_cast<const uint4*>(ap[rt]);
    #pragma unroll
    for (int nf = 0; nf < 4; nf++)
        bv[0][nf] = *reinterpret_cast<const uint4*>(bp + nf * 4096);
    #pragma unroll
    for (int ks = 0; ks < 8; ks++) {
        const int cur = ks & 1, nxt = cur ^ 1;
        if (ks < 7) {
            #pragma unroll
            for (int rt = 0; rt < 4; rt++)
                av[nxt][rt] = *reinterpret_cast<const uint4*>(ap[rt] + (ks + 1) * 32);
            #pragma unroll
            for (int nf = 0; nf < 4; nf++)
                bv[nxt][nf] = *reinterpret_cast<const uint4*>(bp + nf * 4096 + (ks + 1) * 512);
        }
        #pragma unroll
        for (int nf = 0; nf < 4; nf++) {
            U4S8 b; b.u = bv[cur][nf];
            #pragma unroll
            for (int rt = 0; rt < 4; rt++) {
                U4S8 A; A.u = av[cur][rt];
                acc[rt][nf] = mfma_bf16(A.s, b.s, acc[rt][nf]);
            }
        }
    }

    #pragma unroll
    for (int rt = 0; rt < 4; rt++) {
        #pragma unroll
        for (int j = 0; j < 4; j++) {
            int m = stile * 64 + rt * 16 + kg * 4 + j;
            if (m >= M) continue;
            if (!routed) {
                float* orow = out + (size_t)m * D_DIM;
                #pragma unroll
                for (int nf = 0; nf < 4; nf++)
                    orow[(nt0 + nf) * 16 + ln] = acc[rt][nf][j];
            } else {
                int tok = list_tok[beg + m];
                float* orow = out + (size_t)tok * D_DIM;
                #pragma unroll
                for (int nf = 0; nf < 4; nf++)
                    atomicAdd(&orow[(nt0 + nf) * 16 + ln], acc[rt][nf][j]);
            }
        }
    }
}

// ---------------------------------------------------------------------------
extern "C" void kernel_launch(void* const* d_in, const int* in_sizes, int n_in,
                              void* d_out, int out_size, void* d_ws, size_t ws_size,
                              hipStream_t stream) {
    const float* x      = (const float*)d_in[0];
    const float* router = (const float*)d_in[1];
    const float* shg    = (const float*)d_in[2];
    const float* shu    = (const float*)d_in[3];
    const float* shd    = (const float*)d_in[4];
    const float* Wg     = (const float*)d_in[5];
    const float* Wu     = (const float*)d_in[6];
    const float* Wd     = (const float*)d_in[7];
    float* out = (float*)d_out;

    // ws layout (~13.5 MB)
    char* ws = (char*)d_ws;
    int*   counts   = (int*)(ws + 0);
    int*   nextp    = (int*)(ws + 64);
    int*   topk_idx = (int*)(ws + 256);
    float* topk_sc  = (float*)(ws + 256 + 1 * 32768);
    int*   list_tok = (int*)(ws + 256 + 2 * 32768);
    float* list_sc  = (float*)(ws + 256 + 3 * 32768);
    unsigned short* WguF = (unsigned short*)(ws + 256 + 4 * 32768);  // 288*16*512 u16 = 4.7MB
    unsigned short* WdF  = WguF + (size_t)288 * 16 * 512;            // 288*8*512 u16 = 2.4MB
    unsigned short* H1s  = WdF + (size_t)288 * 8 * 512;              // 4096*256 bf16
    unsigned short* H1r  = H1s + (size_t)N_TOK * H_DIM;              // 8192*256 bf16

    hipLaunchKernelGGL(init_kernel,   dim3(1),   dim3(64),  0, stream, counts, nextp);
    hipLaunchKernelGGL(router_kernel, dim3(256), dim3(256), 0, stream,
                       x, router, topk_idx, topk_sc, counts);
    hipLaunchKernelGGL(place_kernel,  dim3(16),  dim3(256), 0, stream,
                       topk_idx, topk_sc, counts, nextp, list_tok, list_sc);
    hipLaunchKernelGGL(prep_frag,     dim3(144), dim3(256), 0, stream,
                       Wg, Wu, shg, shu, Wd, shd, WguF, WdF);
    hipLaunchKernelGGL(gemm1_kernel,  dim3(16, 4, 9), dim3(256), 0, stream,
                       x, WguF, counts, list_tok, list_sc, H1s, H1r);
    hipLaunchKernelGGL(down_kernel,   dim3(16, 8, 1), dim3(256), 0, stream,
                       H1s, H1r, WdF, counts, list_tok, out, 0);
    hipLaunchKernelGGL(down_kernel,   dim3(16, 8, 8), dim3(256), 0, stream,
                       H1s, H1r, WdF, counts, list_tok, out, 1);
}

// Round 11
// 180.931 us; speedup vs baseline: 1.5972x; 1.5972x over previous
//
#include <hip/hip_runtime.h>
#include <hip/hip_bf16.h>
#include <math.h>

#define N_TOK 4096
#define D_DIM 512
#define E_NUM 8
#define H_DIM 256

typedef __attribute__((ext_vector_type(8))) short short8v;   // 8 bf16
typedef __attribute__((ext_vector_type(4))) float floatx4;   // MFMA acc

union U4S8 { uint4 u; short8v s; };

__device__ inline floatx4 mfma_bf16(short8v a, short8v b, floatx4 c) {
    return __builtin_amdgcn_mfma_f32_16x16x32_bf16(a, b, c, 0, 0, 0);
}

__device__ inline unsigned short f2bf(float f) {           // RNE fp32->bf16
    union { float f; unsigned u; } v; v.f = f;
    unsigned r = v.u + 0x7FFFu + ((v.u >> 16) & 1u);
    return (unsigned short)(r >> 16);
}
__device__ inline unsigned pack2(float a, float b) {
    return (unsigned)f2bf(a) | ((unsigned)f2bf(b) << 16);
}
__device__ inline void calc_offs(const int* __restrict__ counts, int* offs) {
    int a = 0;
    #pragma unroll
    for (int e = 0; e < E_NUM; e++) { offs[e] = a; a += counts[e]; }
    offs[E_NUM] = a;
}

// ---------------------------------------------------------------------------
__global__ void init_kernel(int* counts, int* nextp) {
    int t = threadIdx.x;
    if (t < 16) { counts[t] = 0; nextp[t] = 0; }
}

// ---------------------------------------------------------------------------
// router v3: wave per 4 tokens, R in regs, exact fp32 top-2; ALSO writes
// x converted to bf16 (xb) so the GEMM A-path needs no fp32 load / cvt.
// ---------------------------------------------------------------------------
__global__ __launch_bounds__(256)
void router_kernel(const float* __restrict__ x, const float* __restrict__ router,
                   int* __restrict__ topk_idx, float* __restrict__ topk_sc,
                   int* __restrict__ counts, unsigned short* __restrict__ xb) {
    __shared__ int csh[E_NUM];
    int t = threadIdx.x;
    if (t < E_NUM) csh[t] = 0;
    __syncthreads();

    int wave = t >> 6, lane = t & 63;
    float R[8][8];
    #pragma unroll
    for (int q = 0; q < 8; q++) {
        #pragma unroll
        for (int h = 0; h < 2; h++) {
            float4 v = *reinterpret_cast<const float4*>(
                router + (size_t)(lane * 8 + q) * E_NUM + h * 4);
            R[q][h * 4 + 0] = v.x; R[q][h * 4 + 1] = v.y;
            R[q][h * 4 + 2] = v.z; R[q][h * 4 + 3] = v.w;
        }
    }
    int cnt[E_NUM];
    #pragma unroll
    for (int e = 0; e < E_NUM; e++) cnt[e] = 0;

    #pragma unroll
    for (int it = 0; it < 4; it++) {
        int n = (blockIdx.x * 4 + wave) * 4 + it;
        const float* xr = x + (size_t)n * D_DIM + lane * 8;
        float4 xa = *reinterpret_cast<const float4*>(xr);
        float4 xb4 = *reinterpret_cast<const float4*>(xr + 4);
        float xs[8] = {xa.x, xa.y, xa.z, xa.w, xb4.x, xb4.y, xb4.z, xb4.w};

        // bf16 copy of x (RNE, same values the GEMM used before)
        uint4 xo;
        xo.x = pack2(xs[0], xs[1]); xo.y = pack2(xs[2], xs[3]);
        xo.z = pack2(xs[4], xs[5]); xo.w = pack2(xs[6], xs[7]);
        *reinterpret_cast<uint4*>(xb + (size_t)n * D_DIM + lane * 8) = xo;

        float acc[E_NUM];
        #pragma unroll
        for (int e = 0; e < E_NUM; e++) acc[e] = 0.f;
        #pragma unroll
        for (int q = 0; q < 8; q++)
            #pragma unroll
            for (int e = 0; e < E_NUM; e++)
                acc[e] = fmaf(xs[q], R[q][e], acc[e]);
        #pragma unroll
        for (int s = 1; s < 64; s <<= 1) {
            #pragma unroll
            for (int e = 0; e < E_NUM; e++)
                acc[e] += __shfl_xor(acc[e], s);
        }
        float mx = acc[0];
        #pragma unroll
        for (int e = 1; e < E_NUM; e++) mx = fmaxf(mx, acc[e]);
        float p[E_NUM], s = 0.f;
        #pragma unroll
        for (int e = 0; e < E_NUM; e++) { p[e] = expf(acc[e] - mx); s += p[e]; }
        float inv = 1.f / s;

        int i0 = 0; float p0 = p[0];
        #pragma unroll
        for (int e = 1; e < E_NUM; e++)
            if (p[e] > p0) { p0 = p[e]; i0 = e; }
        int i1 = -1; float p1 = -1.f;
        #pragma unroll
        for (int e = 0; e < E_NUM; e++)
            if (e != i0 && p[e] > p1) { p1 = p[e]; i1 = e; }

        if (lane == 0) {
            topk_idx[n * 2 + 0] = i0;
            topk_idx[n * 2 + 1] = i1;
            topk_sc[n * 2 + 0]  = p0 * inv;
            topk_sc[n * 2 + 1]  = p1 * inv;
            #pragma unroll
            for (int e = 0; e < E_NUM; e++)
                cnt[e] += (i0 == e) + (i1 == e);
        }
    }
    if (lane == 0) {
        #pragma unroll
        for (int e = 0; e < E_NUM; e++)
            if (cnt[e]) atomicAdd(&csh[e], cnt[e]);
    }
    __syncthreads();
    if (t < E_NUM && csh[t]) atomicAdd(&counts[t], csh[t]);
}

// ---------------------------------------------------------------------------
// place (unchanged)
// ---------------------------------------------------------------------------
__global__ __launch_bounds__(256)
void place_kernel(const int* __restrict__ topk_idx, const float* __restrict__ topk_sc,
                  const int* __restrict__ counts, int* __restrict__ nextp,
                  int* __restrict__ list_tok, float* __restrict__ list_sc) {
    int offs[E_NUM + 1];
    calc_offs(counts, offs);
    int n = blockIdx.x * 256 + threadIdx.x;
    int lane = threadIdx.x & 63;
    for (int k = 0; k < 2; k++) {
        int e = topk_idx[n * 2 + k];
        float sc = topk_sc[n * 2 + k];
        #pragma unroll
        for (int ee = 0; ee < E_NUM; ee++) {
            unsigned long long m = __ballot(e == ee);
            if (m == 0ull) continue;
            int leader = __ffsll((long long)m) - 1;
            int base = 0;
            if (lane == leader) base = atomicAdd(&nextp[ee], (int)__popcll(m));
            base = __shfl(base, leader);
            if (e == ee) {
                int pos = base + (int)__popcll(m & ((1ull << lane) - 1ull));
                int slot = offs[ee] + pos;
                list_tok[slot] = n;
                list_sc[slot]  = sc;
            }
        }
    }
}

// ---------------------------------------------------------------------------
// prep_frag v2: one wave per (panel, kstep) -> 6912 wave-jobs (12x TLP).
// Layouts identical to round-9 version.
// ---------------------------------------------------------------------------
__global__ __launch_bounds__(256)
void prep_frag(const float* __restrict__ Wg, const float* __restrict__ Wu,
               const float* __restrict__ shg, const float* __restrict__ shu,
               const float* __restrict__ Wd, const float* __restrict__ shd,
               unsigned short* __restrict__ WguF, unsigned short* __restrict__ WdF) {
    int wid = threadIdx.x >> 6, lane = threadIdx.x & 63;
    int job = blockIdx.x * 4 + wid;
    int kg = lane >> 4, ln = lane & 15;
    if (job < 4608) {                                  // gate/up: 288 panels x 16 ks
        int panel = job >> 4, ks = job & 15;
        int e = panel >> 5, r = panel & 31, gu = r >> 4, nt = r & 15;
        const float* S = (e < E_NUM) ? ((gu ? Wu : Wg) + (size_t)e * 131072)
                                     : (gu ? shu : shg);
        unsigned short* D = WguF + ((size_t)((e * 2 + gu) * 16 + nt) * 16 + ks) * 512 + lane * 8;
        float v[8];
        #pragma unroll
        for (int j = 0; j < 8; j++)
            v[j] = S[(size_t)(ks * 32 + kg * 8 + j) * H_DIM + nt * 16 + ln];
        uint4 o;
        o.x = pack2(v[0], v[1]); o.y = pack2(v[2], v[3]);
        o.z = pack2(v[4], v[5]); o.w = pack2(v[6], v[7]);
        *reinterpret_cast<uint4*>(D) = o;
    } else if (job < 6912) {                           // down: 288 panels x 8 ks
        int j2 = job - 4608;
        int panel = j2 >> 3, ks = j2 & 7;
        int e = panel >> 5, nt = panel & 31;
        const float* S = (e < E_NUM) ? (Wd + (size_t)e * 131072) : shd;
        unsigned short* D = WdF + ((size_t)(e * 32 + nt) * 8 + ks) * 512 + lane * 8;
        float v[8];
        #pragma unroll
        for (int j = 0; j < 8; j++)
            v[j] = S[(size_t)(ks * 32 + kg * 8 + j) * D_DIM + nt * 16 + ln];
        uint4 o;
        o.x = pack2(v[0], v[1]); o.y = pack2(v[2], v[3]);
        o.z = pack2(v[4], v[5]); o.w = pack2(v[6], v[7]);
        *reinterpret_cast<uint4*>(D) = o;
    }
}

// ---------------------------------------------------------------------------
// gemm1 v5: barrier-free, LDS-free, rt=1 (v3 geometry: 3072 waves), bf16 A,
// depth-2 prefetch via 3-slot ring (fully unrolled -> static indices).
// grid (64, 4, 9): stile = bx*4+wid, nt0 = by*4, z = expert (8=shared).
// ---------------------------------------------------------------------------
__global__ __launch_bounds__(256)
void gemm1_kernel(const unsigned short* __restrict__ xb, const unsigned short* __restrict__ WguF,
                  const int* __restrict__ counts, const int* __restrict__ list_tok,
                  const float* __restrict__ list_sc,
                  unsigned short* __restrict__ H1s, unsigned short* __restrict__ H1r) {
    int ez = blockIdx.z;
    int offs[E_NUM + 1];
    calc_offs(counts, offs);
    int beg = 0, M;
    if (ez == E_NUM) { M = N_TOK; }
    else { beg = offs[ez]; M = counts[ez]; }
    int wid = threadIdx.x >> 6, lane = threadIdx.x & 63;
    int stile = blockIdx.x * 4 + wid;
    if (stile * 16 >= M) return;
    int nt0 = blockIdx.y * 4;
    int kg = lane >> 4, ln = lane & 15;

    int m_lane = stile * 16 + ln;
    int srow;
    if (ez == E_NUM) srow = m_lane;
    else srow = list_tok[beg + (m_lane < M ? m_lane : M - 1)];
    const unsigned short* ap = xb + (size_t)srow * D_DIM + kg * 8;

    const unsigned short* bgp = WguF + ((size_t)((ez * 2 + 0) * 16 + nt0) * 16) * 512 + lane * 8;
    const unsigned short* bup = WguF + ((size_t)((ez * 2 + 1) * 16 + nt0) * 16) * 512 + lane * 8;

    floatx4 zf = {0.f, 0.f, 0.f, 0.f};
    floatx4 accg[4], accu[4];
    #pragma unroll
    for (int nf = 0; nf < 4; nf++) { accg[nf] = zf; accu[nf] = zf; }

    uint4 aB[3];
    uint4 vg[3][4], vu[3][4];
    // prologue: ks=0 and ks=1 in flight
    #pragma unroll
    for (int pk = 0; pk < 2; pk++) {
        aB[pk] = *reinterpret_cast<const uint4*>(ap + pk * 32);
        #pragma unroll
        for (int nf = 0; nf < 4; nf++) {
            vg[pk][nf] = *reinterpret_cast<const uint4*>(bgp + nf * 8192 + pk * 512);
            vu[pk][nf] = *reinterpret_cast<const uint4*>(bup + nf * 8192 + pk * 512);
        }
    }
    #pragma unroll
    for (int ks = 0; ks < 16; ks++) {
        const int cur = ks % 3;
        if (ks + 2 < 16) {
            const int pf = (ks + 2) % 3;
            aB[pf] = *reinterpret_cast<const uint4*>(ap + (ks + 2) * 32);
            #pragma unroll
            for (int nf = 0; nf < 4; nf++) {
                vg[pf][nf] = *reinterpret_cast<const uint4*>(bgp + nf * 8192 + (ks + 2) * 512);
                vu[pf][nf] = *reinterpret_cast<const uint4*>(bup + nf * 8192 + (ks + 2) * 512);
            }
        }
        U4S8 A; A.u = aB[cur];
        #pragma unroll
        for (int nf = 0; nf < 4; nf++) {
            U4S8 g, u; g.u = vg[cur][nf]; u.u = vu[cur][nf];
            accg[nf] = mfma_bf16(A.s, g.s, accg[nf]);
            accu[nf] = mfma_bf16(A.s, u.s, accu[nf]);
        }
    }

    // epilogue: C/D row=(l>>4)*4+j, col=l&15. silu(g)*u (*score), bf16 store.
    #pragma unroll
    for (int j = 0; j < 4; j++) {
        int m = stile * 16 + kg * 4 + j;
        if (m >= M) continue;
        float sc = 1.f;
        unsigned short* drow;
        if (ez == E_NUM) drow = H1s + (size_t)m * H_DIM;
        else { sc = list_sc[beg + m]; drow = H1r + (size_t)(beg + m) * H_DIM; }
        #pragma unroll
        for (int nf = 0; nf < 4; nf++) {
            float g = accg[nf][j];
            float u = accu[nf][j];
            float h = g / (1.f + expf(-g)) * u * sc;
            drow[(nt0 + nf) * 16 + ln] = f2bf(h);
        }
    }
}

// ---------------------------------------------------------------------------
// down v5: barrier-free, LDS-free, rt=1, depth-2 prefetch (3-slot ring).
// routed=0: shared expert, plain stores cover all of out (runs first).
// routed=1: per-expert atomicAdd.
// ---------------------------------------------------------------------------
__global__ __launch_bounds__(256)
void down_kernel(const unsigned short* __restrict__ H1s, const unsigned short* __restrict__ H1r,
                 const unsigned short* __restrict__ WdF, const int* __restrict__ counts,
                 const int* __restrict__ list_tok, float* __restrict__ out, int routed) {
    int beg = 0, M, eidx;
    if (routed) {
        int e = blockIdx.z;
        int offs[E_NUM + 1];
        calc_offs(counts, offs);
        beg = offs[e]; M = counts[e]; eidx = e;
    } else { M = N_TOK; eidx = E_NUM; }
    int wid = threadIdx.x >> 6, lane = threadIdx.x & 63;
    int stile = blockIdx.x * 4 + wid;
    if (stile * 16 >= M) return;
    int nt0 = blockIdx.y * 4;
    int kg = lane >> 4, ln = lane & 15;

    const unsigned short* H1 = routed ? H1r : H1s;
    int m_lane = stile * 16 + ln;
    const unsigned short* ap = H1 + (size_t)(beg + (m_lane < M ? m_lane : M - 1)) * H_DIM + kg * 8;
    const unsigned short* bp = WdF + ((size_t)(eidx * 32 + nt0) * 8) * 512 + lane * 8;

    floatx4 zf = {0.f, 0.f, 0.f, 0.f};
    floatx4 acc[4];
    #pragma unroll
    for (int nf = 0; nf < 4; nf++) acc[nf] = zf;

    uint4 aB[3], bv[3][4];
    #pragma unroll
    for (int pk = 0; pk < 2; pk++) {
        aB[pk] = *reinterpret_cast<const uint4*>(ap + pk * 32);
        #pragma unroll
        for (int nf = 0; nf < 4; nf++)
            bv[pk][nf] = *reinterpret_cast<const uint4*>(bp + nf * 4096 + pk * 512);
    }
    #pragma unroll
    for (int ks = 0; ks < 8; ks++) {
        const int cur = ks % 3;
        if (ks + 2 < 8) {
            const int pf = (ks + 2) % 3;
            aB[pf] = *reinterpret_cast<const uint4*>(ap + (ks + 2) * 32);
            #pragma unroll
            for (int nf = 0; nf < 4; nf++)
                bv[pf][nf] = *reinterpret_cast<const uint4*>(bp + nf * 4096 + (ks + 2) * 512);
        }
        U4S8 A; A.u = aB[cur];
        #pragma unroll
        for (int nf = 0; nf < 4; nf++) {
            U4S8 b; b.u = bv[cur][nf];
            acc[nf] = mfma_bf16(A.s, b.s, acc[nf]);
        }
    }

    #pragma unroll
    for (int j = 0; j < 4; j++) {
        int m = stile * 16 + kg * 4 + j;
        if (m >= M) continue;
        if (!routed) {
            float* orow = out + (size_t)m * D_DIM;
            #pragma unroll
            for (int nf = 0; nf < 4; nf++)
                orow[(nt0 + nf) * 16 + ln] = acc[nf][j];
        } else {
            int tok = list_tok[beg + m];
            float* orow = out + (size_t)tok * D_DIM;
            #pragma unroll
            for (int nf = 0; nf < 4; nf++)
                atomicAdd(&orow[(nt0 + nf) * 16 + ln], acc[nf][j]);
        }
    }
}

// ---------------------------------------------------------------------------
extern "C" void kernel_launch(void* const* d_in, const int* in_sizes, int n_in,
                              void* d_out, int out_size, void* d_ws, size_t ws_size,
                              hipStream_t stream) {
    const float* x      = (const float*)d_in[0];
    const float* router = (const float*)d_in[1];
    const float* shg    = (const float*)d_in[2];
    const float* shu    = (const float*)d_in[3];
    const float* shd    = (const float*)d_in[4];
    const float* Wg     = (const float*)d_in[5];
    const float* Wu     = (const float*)d_in[6];
    const float* Wd     = (const float*)d_in[7];
    float* out = (float*)d_out;

    // ws layout (~17.7 MB)
    char* ws = (char*)d_ws;
    int*   counts   = (int*)(ws + 0);
    int*   nextp    = (int*)(ws + 64);
    int*   topk_idx = (int*)(ws + 256);
    float* topk_sc  = (float*)(ws + 256 + 1 * 32768);
    int*   list_tok = (int*)(ws + 256 + 2 * 32768);
    float* list_sc  = (float*)(ws + 256 + 3 * 32768);
    unsigned short* WguF = (unsigned short*)(ws + 256 + 4 * 32768);  // 288*16*512 u16
    unsigned short* WdF  = WguF + (size_t)288 * 16 * 512;            // 288*8*512 u16
    unsigned short* H1s  = WdF + (size_t)288 * 8 * 512;              // 4096*256 bf16
    unsigned short* H1r  = H1s + (size_t)N_TOK * H_DIM;              // 8192*256 bf16
    unsigned short* xb   = H1r + (size_t)2 * N_TOK * H_DIM;          // 4096*512 bf16

    hipLaunchKernelGGL(init_kernel,   dim3(1),    dim3(64),  0, stream, counts, nextp);
    hipLaunchKernelGGL(router_kernel, dim3(256),  dim3(256), 0, stream,
                       x, router, topk_idx, topk_sc, counts, xb);
    hipLaunchKernelGGL(place_kernel,  dim3(16),   dim3(256), 0, stream,
                       topk_idx, topk_sc, counts, nextp, list_tok, list_sc);
    hipLaunchKernelGGL(prep_frag,     dim3(1728), dim3(256), 0, stream,
                       Wg, Wu, shg, shu, Wd, shd, WguF, WdF);
    hipLaunchKernelGGL(gemm1_kernel,  dim3(64, 4, 9), dim3(256), 0, stream,
                       xb, WguF, counts, list_tok, list_sc, H1s, H1r);
    hipLaunchKernelGGL(down_kernel,   dim3(64, 8, 1), dim3(256), 0, stream,
                       H1s, H1r, WdF, counts, list_tok, out, 0);
    hipLaunchKernelGGL(down_kernel,   dim3(64, 8, 8), dim3(256), 0, stream,
                       H1s, H1r, WdF, counts, list_tok, out, 1);
}